// Round 8
// baseline (424.899 us; speedup 1.0000x reference)
//
#include <hip/hip_runtime.h>

#define B_ 8
#define N_ 8192
#define S_ 2048
#define D1_ 128
#define D2_ 256
#define C0_ 384
#define C1_ 256
#define C2_ 128
#define BN_EPS 1e-5f

typedef unsigned long long ull;
typedef unsigned short u16;
typedef __bf16 bf16x8 __attribute__((ext_vector_type(8)));
typedef float f32x4 __attribute__((ext_vector_type(4)));
typedef short short8_ __attribute__((ext_vector_type(8)));

__device__ __forceinline__ u16 f2bf(float x) {
  unsigned int u = __float_as_uint(x);
  unsigned int r = u + 0x7fffu + ((u >> 16) & 1u);
  return (u16)(r >> 16);
}
__device__ __forceinline__ float bf2f(u16 h) {
  return __uint_as_float(((unsigned int)h) << 16);
}

// async global->LDS DMA, 16B per lane. LDS dest must be wave-uniform;
// HW writes dest + lane*16 (m104). Global src is per-lane.
__device__ __forceinline__ void gld16(const void* g, void* l) {
  __builtin_amdgcn_global_load_lds(
      (const __attribute__((address_space(1))) void*)g,
      (__attribute__((address_space(3))) void*)l,
      16, 0, 0);
}

// branchless sorted-insert of key k into ascending top-3 (k0<=k1<=k2)
__device__ __forceinline__ void ins3(ull k, ull& k0, ull& k1, ull& k2) {
  ull t = k < k2 ? k : k2;
  ull u = k1 < t ? k1 : t;
  k2 = k1 < t ? t : k1;
  k1 = k0 < u ? u : k0;
  k0 = k0 < u ? k0 : u;
}

// ---------------------------------------------------------------------------
__global__ void cvt_bf16_kernel(const float* __restrict__ src, u16* __restrict__ dst, int n)
{
  int i = blockIdx.x * blockDim.x + threadIdx.x;
  if (i < n) dst[i] = f2bf(src[i]);
}

// ---------------------------------------------------------------------------
// transpose points_now [B][D2][S] -> pnT [B][S][D2]  (fp32, for knn gather)
// ---------------------------------------------------------------------------
__global__ __launch_bounds__(256) void transpose_kernel(
    const float* __restrict__ in, float* __restrict__ out)
{
  __shared__ float tile[32][33];
  const int b  = blockIdx.z;
  const int s0 = blockIdx.x * 32;
  const int d0 = blockIdx.y * 32;
  const int tx = threadIdx.x & 31, ty = threadIdx.x >> 5;

  const float* inb = in + ((size_t)b * D2_ + d0) * S_ + s0;
  #pragma unroll
  for (int r = 0; r < 4; ++r) {
    int d = r * 8 + ty;
    tile[d][tx] = inb[(size_t)d * S_ + tx];
  }
  __syncthreads();
  float* outb = out + ((size_t)b * S_ + s0) * D2_ + d0;
  #pragma unroll
  for (int r = 0; r < 4; ++r) {
    int s = r * 8 + ty;
    outb[(size_t)s * D2_ + tx] = tile[tx][s];
  }
}

// ---------------------------------------------------------------------------
// transpose+convert points_sa [B][D1][N] f32 -> xcat[...][0..127] bf16
// (xcat row stride C0_=384)
// ---------------------------------------------------------------------------
__global__ __launch_bounds__(256) void psaT_kernel(
    const float* __restrict__ in, u16* __restrict__ xcat)
{
  __shared__ float tile[32][33];
  const int b  = blockIdx.z;
  const int n0 = blockIdx.x * 32;
  const int d0 = blockIdx.y * 32;
  const int tx = threadIdx.x & 31, ty = threadIdx.x >> 5;

  const float* inb = in + ((size_t)b * D1_ + d0) * N_ + n0;
  #pragma unroll
  for (int r = 0; r < 4; ++r) {
    int d = r * 8 + ty;
    tile[d][tx] = inb[(size_t)d * N_ + tx];
  }
  __syncthreads();
  u16* outb = xcat + ((size_t)b * N_ + n0) * C0_ + d0;
  #pragma unroll
  for (int r = 0; r < 4; ++r) {
    int n = r * 8 + ty;
    outb[(size_t)n * C0_ + tx] = f2bf(tile[tx][n]);
  }
}

// ---------------------------------------------------------------------------
// K1: 3-NN + interpolation. 128 queries/block. Writes xcat cols 128..383.
// ---------------------------------------------------------------------------
__global__ __launch_bounds__(256) void knn_interp_kernel(
    const float* __restrict__ xyz_sa, const float* __restrict__ xyz_now,
    const float* __restrict__ pnT, u16* __restrict__ xcat)
{
  __shared__ float4 sp[S_];
  __shared__ int   s_idx[128][3];
  __shared__ float s_w[128][3];

  const int b  = blockIdx.y;
  const int n0 = blockIdx.x * 128;

  const float* xb = xyz_now + (size_t)b * 3 * S_;
  for (int i = threadIdx.x; i < S_; i += 256) {
    float px = xb[i], py = xb[S_ + i], pz = xb[2 * S_ + i];
    sp[i] = make_float4(px, py, pz, px * px + py * py + pz * pz);
  }
  __syncthreads();

  const int qg = threadIdx.x >> 3;   // 0..31 query group (4 queries)
  const int t  = threadIdx.x & 7;    // scanner 0..7
  const int nb = n0 + qg * 4;

  const float* xq = xyz_sa + (size_t)b * 3 * N_;
  float qx[4], qy[4], qz[4], qq[4];
  #pragma unroll
  for (int w = 0; w < 4; ++w) {
    int n = nb + w;
    qx[w] = xq[n]; qy[w] = xq[N_ + n]; qz[w] = xq[2 * N_ + n];
    qq[w] = qx[w] * qx[w] + qy[w] * qy[w] + qz[w] * qz[w];
  }

  ull K0[4], K1[4], K2[4];
  #pragma unroll
  for (int w = 0; w < 4; ++w) { K0[w] = ~0ull; K1[w] = ~0ull; K2[w] = ~0ull; }

  #pragma unroll 2
  for (int it = 0; it < S_ / 8; ++it) {
    int s = (it << 3) | t;
    float4 p = sp[s];
    #pragma unroll
    for (int w = 0; w < 4; ++w) {
      float dot = qx[w] * p.x + qy[w] * p.y + qz[w] * p.z;
      float d = qq[w] - 2.0f * dot + p.w;
      unsigned int bits = __float_as_uint(d);
      unsigned int u = bits ^ (0x80000000u | (unsigned int)((int)bits >> 31));
      ull k = ((ull)u << 32) | (unsigned int)s;
      ins3(k, K0[w], K1[w], K2[w]);
    }
  }

  #pragma unroll
  for (int m = 1; m <= 4; m <<= 1) {
    #pragma unroll
    for (int w = 0; w < 4; ++w) {
      ull o0 = __shfl_xor(K0[w], m), o1 = __shfl_xor(K1[w], m), o2 = __shfl_xor(K2[w], m);
      ins3(o0, K0[w], K1[w], K2[w]);
      ins3(o1, K0[w], K1[w], K2[w]);
      ins3(o2, K0[w], K1[w], K2[w]);
    }
  }

  if (t == 0) {
    #pragma unroll
    for (int w = 0; w < 4; ++w) {
      unsigned int u0 = (unsigned int)(K0[w] >> 32);
      unsigned int u1 = (unsigned int)(K1[w] >> 32);
      unsigned int u2 = (unsigned int)(K2[w] >> 32);
      float d0 = __uint_as_float(u0 ^ (0x80000000u | ~(unsigned int)((int)u0 >> 31)));
      float d1 = __uint_as_float(u1 ^ (0x80000000u | ~(unsigned int)((int)u1 >> 31)));
      float d2 = __uint_as_float(u2 ^ (0x80000000u | ~(unsigned int)((int)u2 >> 31)));
      float r0 = 1.0f / (d0 + 1e-8f);
      float r1 = 1.0f / (d1 + 1e-8f);
      float r2 = 1.0f / (d2 + 1e-8f);
      float rs = 1.0f / (r0 + r1 + r2);
      int qi = qg * 4 + w;
      s_idx[qi][0] = (int)(K0[w] & 0xFFFFFFFFu);
      s_idx[qi][1] = (int)(K1[w] & 0xFFFFFFFFu);
      s_idx[qi][2] = (int)(K2[w] & 0xFFFFFFFFu);
      s_w[qi][0] = r0 * rs; s_w[qi][1] = r1 * rs; s_w[qi][2] = r2 * rs;
    }
  }
  __syncthreads();

  const int wave = threadIdx.x >> 6;
  const int lane = threadIdx.x & 63;
  const float* pb = pnT + (size_t)b * S_ * D2_;
  u16* ob = xcat + ((size_t)b * N_ + n0) * C0_ + D1_;   // cols 128..383
  #pragma unroll 2
  for (int i = 0; i < 32; ++i) {
    const int qi = wave * 32 + i;
    const int j0 = s_idx[qi][0], j1 = s_idx[qi][1], j2 = s_idx[qi][2];
    const float w0 = s_w[qi][0], w1 = s_w[qi][1], w2 = s_w[qi][2];
    float4 f0 = *(const float4*)(pb + (size_t)j0 * D2_ + lane * 4);
    float4 f1 = *(const float4*)(pb + (size_t)j1 * D2_ + lane * 4);
    float4 f2 = *(const float4*)(pb + (size_t)j2 * D2_ + lane * 4);
    float rx = w0 * f0.x + w1 * f1.x + w2 * f2.x;
    float ry = w0 * f0.y + w1 * f1.y + w2 * f2.y;
    float rz = w0 * f0.z + w1 * f1.z + w2 * f2.z;
    float rw = w0 * f0.w + w1 * f1.w + w2 * f2.w;
    unsigned int lo = (unsigned int)f2bf(rx) | ((unsigned int)f2bf(ry) << 16);
    unsigned int hi = (unsigned int)f2bf(rz) | ((unsigned int)f2bf(rw) << 16);
    *(uint2*)(ob + (size_t)qi * C0_ + lane * 4) = make_uint2(lo, hi);
  }
}

// ---------------------------------------------------------------------------
// Shared-memory union for the MFMA GEMMs: linear staging tiles (required by
// global_load_lds) + epilogue transpose tile.
// ---------------------------------------------------------------------------
union SMg {
  struct { u16 As[2][4096]; u16 Bs[2][4096]; } p;   // [128 rows][32 k] x dbuf
  u16 stage[128][136];
};

// ---------------------------------------------------------------------------
// GEMM1 (m97-style): y0b[b,n,o] = W0[o,:] . xcat[b,n,:] + b0[o]; + stats.
// global_load_lds staging, linear LDS, 1 barrier/K-step double buffer.
// ---------------------------------------------------------------------------
__global__ __launch_bounds__(256) void gemm1_mfma_kernel(
    const u16* __restrict__ xcat, const u16* __restrict__ W0b,
    const float* __restrict__ b0, u16* __restrict__ y0b, float* __restrict__ stats)
{
  __shared__ SMg sm;

  const int bz = blockIdx.z;
  const int n0 = blockIdx.x * 128;
  const int o0 = blockIdx.y * 128;
  const int tid = threadIdx.x;
  const int wid = tid >> 6, lane = tid & 63;
  const int wo = wid & 1, wn = wid >> 1;
  const int m = lane & 15, g = lane >> 4;
  const int lr = lane >> 2, lc = (lane & 3) << 3;   // row-in-16, col (u16)

  f32x4 acc[4][4];
  #pragma unroll
  for (int i = 0; i < 4; ++i)
    #pragma unroll
    for (int j = 0; j < 4; ++j) acc[i][j] = (f32x4){0.f, 0.f, 0.f, 0.f};

  auto STAGE = [&](int buf, int kt) {
    #pragma unroll
    for (int i2 = 0; i2 < 2; ++i2) {
      const int i = wid * 2 + i2;            // 0..7, 16 rows each
      const int row = i * 16 + lr;
      gld16(W0b  + (size_t)(o0 + row) * C0_ + kt + lc, &sm.p.As[buf][i * 512]);
      gld16(xcat + (size_t)(bz * N_ + n0 + row) * C0_ + kt + lc, &sm.p.Bs[buf][i * 512]);
    }
  };

  STAGE(0, 0);
  __syncthreads();                            // drain vmcnt -> tile0 ready

  for (int kt = 0; kt < 12; ++kt) {
    const int cur = kt & 1;
    if (kt < 11) STAGE(cur ^ 1, (kt + 1) << 5);   // async, no reg round-trip

    bf16x8 af[4], bfv[4];
    #pragma unroll
    for (int f = 0; f < 4; ++f)
      af[f] = __builtin_bit_cast(bf16x8,
          *(const short8_*)&sm.p.As[cur][(wo * 64 + f * 16 + m) * 32 + g * 8]);
    #pragma unroll
    for (int f = 0; f < 4; ++f)
      bfv[f] = __builtin_bit_cast(bf16x8,
          *(const short8_*)&sm.p.Bs[cur][(wn * 64 + f * 16 + m) * 32 + g * 8]);
    #pragma unroll
    for (int i = 0; i < 4; ++i)
      #pragma unroll
      for (int j = 0; j < 4; ++j)
        acc[i][j] = __builtin_amdgcn_mfma_f32_16x16x32_bf16(af[i], bfv[j], acc[i][j], 0, 0, 0);

    __syncthreads();   // next tile landed + all waves done with cur
  }

  // epilogue: bias + stats; stage [n][o] in LDS, then coalesced stream-out
  #pragma unroll
  for (int of = 0; of < 4; ++of) {
    const int ol = wo * 64 + of * 16 + g * 4;
    const int ob = o0 + ol;
    float bias[4], s1[4], s2[4];
    #pragma unroll
    for (int r = 0; r < 4; ++r) { bias[r] = b0[ob + r]; s1[r] = 0.f; s2[r] = 0.f; }
    #pragma unroll
    for (int nf = 0; nf < 4; ++nf) {
      const int nl = wn * 64 + nf * 16 + m;
      float y[4];
      #pragma unroll
      for (int r = 0; r < 4; ++r) {
        y[r] = acc[of][nf][r] + bias[r];
        s1[r] += y[r]; s2[r] += y[r] * y[r];
      }
      unsigned int lo = (unsigned int)f2bf(y[0]) | ((unsigned int)f2bf(y[1]) << 16);
      unsigned int hi = (unsigned int)f2bf(y[2]) | ((unsigned int)f2bf(y[3]) << 16);
      *(uint2*)&sm.stage[nl][ol] = make_uint2(lo, hi);
    }
    #pragma unroll
    for (int mk = 1; mk < 16; mk <<= 1)
      #pragma unroll
      for (int r = 0; r < 4; ++r) {
        s1[r] += __shfl_xor(s1[r], mk);
        s2[r] += __shfl_xor(s2[r], mk);
      }
    if (m == 0) {
      #pragma unroll
      for (int r = 0; r < 4; ++r) {
        atomicAdd(&stats[ob + r], s1[r]);
        atomicAdd(&stats[C1_ + ob + r], s2[r]);
      }
    }
  }
  __syncthreads();
  {
    const int rrow = tid >> 4;
    const int col  = (tid & 15) * 8;
    #pragma unroll
    for (int pass = 0; pass < 8; ++pass) {
      const int r = pass * 16 + rrow;
      uint4 v = *(const uint4*)&sm.stage[r][col];
      *(uint4*)(y0b + (size_t)(bz * N_ + n0 + r) * C1_ + o0 + col) = v;
    }
  }
}

// ---------------------------------------------------------------------------
// BN0 + ReLU elementwise: y0r[b,n,c] = relu(y0b*a + c)   (bf16 -> bf16)
// ---------------------------------------------------------------------------
__global__ __launch_bounds__(256) void bn0relu_kernel(
    const u16* __restrict__ y0b, const float* __restrict__ coef, u16* __restrict__ y0r)
{
  __shared__ float cfa[C1_], cfc[C1_];
  cfa[threadIdx.x] = coef[threadIdx.x];
  cfc[threadIdx.x] = coef[C1_ + threadIdx.x];
  __syncthreads();
  const size_t total8 = (size_t)B_ * N_ * C1_ / 8;
  const size_t stride = (size_t)gridDim.x * blockDim.x;
  for (size_t i = (size_t)blockIdx.x * blockDim.x + threadIdx.x; i < total8; i += stride) {
    uint4 v = *(const uint4*)(y0b + i * 8);
    const int ch = (int)((i * 8) & (C1_ - 1));
    float f0 = fmaxf(0.f, fmaf(bf2f((u16)(v.x & 0xffff)), cfa[ch + 0], cfc[ch + 0]));
    float f1 = fmaxf(0.f, fmaf(bf2f((u16)(v.x >> 16)),    cfa[ch + 1], cfc[ch + 1]));
    float f2 = fmaxf(0.f, fmaf(bf2f((u16)(v.y & 0xffff)), cfa[ch + 2], cfc[ch + 2]));
    float f3 = fmaxf(0.f, fmaf(bf2f((u16)(v.y >> 16)),    cfa[ch + 3], cfc[ch + 3]));
    float f4 = fmaxf(0.f, fmaf(bf2f((u16)(v.z & 0xffff)), cfa[ch + 4], cfc[ch + 4]));
    float f5 = fmaxf(0.f, fmaf(bf2f((u16)(v.z >> 16)),    cfa[ch + 5], cfc[ch + 5]));
    float f6 = fmaxf(0.f, fmaf(bf2f((u16)(v.w & 0xffff)), cfa[ch + 6], cfc[ch + 6]));
    float f7 = fmaxf(0.f, fmaf(bf2f((u16)(v.w >> 16)),    cfa[ch + 7], cfc[ch + 7]));
    uint4 o;
    o.x = (unsigned int)f2bf(f0) | ((unsigned int)f2bf(f1) << 16);
    o.y = (unsigned int)f2bf(f2) | ((unsigned int)f2bf(f3) << 16);
    o.z = (unsigned int)f2bf(f4) | ((unsigned int)f2bf(f5) << 16);
    o.w = (unsigned int)f2bf(f6) | ((unsigned int)f2bf(f7) << 16);
    *(uint4*)(y0r + i * 8) = o;
  }
}

// ---------------------------------------------------------------------------
// GEMM2 (m97-style): y1b[b,p,n] = W1[p,:] . y0r[b,n,:] + b1[p]; + stats.
// ---------------------------------------------------------------------------
__global__ __launch_bounds__(256) void gemm2_mfma_kernel(
    const u16* __restrict__ y0r, const u16* __restrict__ W1b,
    const float* __restrict__ b1, u16* __restrict__ y1b, float* __restrict__ stats)
{
  __shared__ SMg sm;

  const int bz = blockIdx.z;
  const int n0 = blockIdx.x * 128;
  const int tid = threadIdx.x;
  const int wid = tid >> 6, lane = tid & 63;
  const int wo = wid & 1, wn = wid >> 1;
  const int m = lane & 15, g = lane >> 4;
  const int lr = lane >> 2, lc = (lane & 3) << 3;

  f32x4 acc[4][4];
  #pragma unroll
  for (int i = 0; i < 4; ++i)
    #pragma unroll
    for (int j = 0; j < 4; ++j) acc[i][j] = (f32x4){0.f, 0.f, 0.f, 0.f};

  auto STAGE = [&](int buf, int kt) {
    #pragma unroll
    for (int i2 = 0; i2 < 2; ++i2) {
      const int i = wid * 2 + i2;
      const int row = i * 16 + lr;
      gld16(W1b + (size_t)row * C1_ + kt + lc, &sm.p.As[buf][i * 512]);
      gld16(y0r + (size_t)(bz * N_ + n0 + row) * C1_ + kt + lc, &sm.p.Bs[buf][i * 512]);
    }
  };

  STAGE(0, 0);
  __syncthreads();

  for (int kt = 0; kt < 8; ++kt) {
    const int cur = kt & 1;
    if (kt < 7) STAGE(cur ^ 1, (kt + 1) << 5);

    bf16x8 af[4], bfv[4];
    #pragma unroll
    for (int f = 0; f < 4; ++f)
      af[f] = __builtin_bit_cast(bf16x8,
          *(const short8_*)&sm.p.As[cur][(wo * 64 + f * 16 + m) * 32 + g * 8]);
    #pragma unroll
    for (int f = 0; f < 4; ++f)
      bfv[f] = __builtin_bit_cast(bf16x8,
          *(const short8_*)&sm.p.Bs[cur][(wn * 64 + f * 16 + m) * 32 + g * 8]);
    #pragma unroll
    for (int i = 0; i < 4; ++i)
      #pragma unroll
      for (int j = 0; j < 4; ++j)
        acc[i][j] = __builtin_amdgcn_mfma_f32_16x16x32_bf16(af[i], bfv[j], acc[i][j], 0, 0, 0);

    __syncthreads();
  }

  // epilogue: stage [p][n] in LDS (y1b is [B][C2][N]); stats as before
  #pragma unroll
  for (int of = 0; of < 4; ++of) {
    const int pb = wo * 64 + of * 16 + g * 4;
    float bias[4], s1[4], s2[4];
    #pragma unroll
    for (int r = 0; r < 4; ++r) { bias[r] = b1[pb + r]; s1[r] = 0.f; s2[r] = 0.f; }
    #pragma unroll
    for (int nf = 0; nf < 4; ++nf) {
      const int nl = wn * 64 + nf * 16 + m;
      #pragma unroll
      for (int r = 0; r < 4; ++r) {
        float y = acc[of][nf][r] + bias[r];
        s1[r] += y; s2[r] += y * y;
        sm.stage[pb + r][nl] = f2bf(y);
      }
    }
    #pragma unroll
    for (int mk = 1; mk < 16; mk <<= 1)
      #pragma unroll
      for (int r = 0; r < 4; ++r) {
        s1[r] += __shfl_xor(s1[r], mk);
        s2[r] += __shfl_xor(s2[r], mk);
      }
    if (m == 0) {
      #pragma unroll
      for (int r = 0; r < 4; ++r) {
        atomicAdd(&stats[pb + r], s1[r]);
        atomicAdd(&stats[C2_ + pb + r], s2[r]);
      }
    }
  }
  __syncthreads();
  {
    #pragma unroll
    for (int pass = 0; pass < 8; ++pass) {
      const int idx = pass * 256 + tid;
      const int p = idx >> 4;
      const int c8 = (idx & 15) * 8;
      uint4 v = *(const uint4*)&sm.stage[p][c8];
      *(uint4*)(y1b + ((size_t)bz * C2_ + p) * N_ + n0 + c8) = v;
    }
  }
}

// ---------------------------------------------------------------------------
__global__ void bn_coef_kernel(const float* __restrict__ g, const float* __restrict__ be,
                               const float* __restrict__ stats, float* __restrict__ coef,
                               int C)
{
  int o = threadIdx.x;
  if (o < C) {
    const float invM = 1.0f / 65536.0f;   // B*N
    float mean = stats[o] * invM;
    float var  = stats[C + o] * invM - mean * mean;
    float a = g[o] / sqrtf(var + BN_EPS);
    float c = be[o] - mean * a;
    coef[o] = a;
    coef[C + o] = c;
  }
}

__global__ void zero_kernel(float* __restrict__ p, int n)
{
  int i = blockIdx.x * blockDim.x + threadIdx.x;
  if (i < n) p[i] = 0.0f;
}

// ---------------------------------------------------------------------------
// final: BN1 + ReLU elementwise, bf16 in -> fp32 out
// ---------------------------------------------------------------------------
__global__ __launch_bounds__(256) void final_kernel(
    const u16* __restrict__ y1b, const float* __restrict__ cf, float* __restrict__ out)
{
  const size_t total4 = (size_t)B_ * C2_ * N_ / 4;
  const size_t stride = (size_t)gridDim.x * blockDim.x;
  for (size_t f = (size_t)blockIdx.x * blockDim.x + threadIdx.x; f < total4; f += stride) {
    size_t base = f * 4;
    int p = (int)((base >> 13) & (C2_ - 1));
    float a = cf[p], c = cf[C2_ + p];
    uint2 v = *(const uint2*)(y1b + base);
    float4 r;
    r.x = fmaxf(0.0f, fmaf(bf2f((u16)(v.x & 0xffff)), a, c));
    r.y = fmaxf(0.0f, fmaf(bf2f((u16)(v.x >> 16)),    a, c));
    r.z = fmaxf(0.0f, fmaf(bf2f((u16)(v.y & 0xffff)), a, c));
    r.w = fmaxf(0.0f, fmaf(bf2f((u16)(v.y >> 16)),    a, c));
    *(float4*)(out + base) = r;
  }
}

// ---------------------------------------------------------------------------
extern "C" void kernel_launch(void* const* d_in, const int* in_sizes, int n_in,
                              void* d_out, int out_size, void* d_ws, size_t ws_size,
                              hipStream_t stream)
{
  const float* xyz_sa     = (const float*)d_in[0];
  const float* xyz_now    = (const float*)d_in[1];
  const float* points_sa  = (const float*)d_in[2];
  const float* points_now = (const float*)d_in[3];
  const float* W0  = (const float*)d_in[4];
  const float* b0  = (const float*)d_in[5];
  const float* g0  = (const float*)d_in[6];
  const float* be0 = (const float*)d_in[7];
  const float* W1  = (const float*)d_in[8];
  const float* b1  = (const float*)d_in[9];
  const float* g1  = (const float*)d_in[10];
  const float* be1 = (const float*)d_in[11];

  const size_t MB = 1048576ull;
  char* base = (char*)d_ws;
  u16*   xcat  = (u16*)(base + 0);            // [B][N][384] bf16  48MB
  u16*   y0r   = (u16*)(base + 0);            // [B][N][256] bf16  32MB (after gemm1; xcat dead)
  float* pnT   = (float*)(base + 48 * MB);    // [B][S][256] f32   16MB (dead after knn)
  u16*   y1b   = (u16*)(base + 48 * MB);      // [B][C2][N] bf16   16MB (overlays pnT)
  u16*   y0b   = (u16*)(base + 64 * MB);      // [B][N][256] bf16  32MB
  u16*   W0b   = (u16*)(base + 96 * MB);      // 98304 bf16
  u16*   W1b   = (u16*)(base + 96 * MB + 512 * 1024); // 32768 bf16
  float* stats = (float*)(base + 97 * MB);    // 768 f
  float* coef  = stats + 768;                 // 768 f
  float* out   = (float*)d_out;

  hipLaunchKernelGGL(zero_kernel, dim3(1), dim3(768), 0, stream, stats, 768);
  hipLaunchKernelGGL(cvt_bf16_kernel, dim3((C1_ * C0_ + 255) / 256), dim3(256), 0, stream,
                     W0, W0b, C1_ * C0_);
  hipLaunchKernelGGL(cvt_bf16_kernel, dim3((C2_ * C1_ + 255) / 256), dim3(256), 0, stream,
                     W1, W1b, C2_ * C1_);
  hipLaunchKernelGGL(transpose_kernel, dim3(S_ / 32, D2_ / 32, B_), dim3(256), 0, stream,
                     points_now, pnT);
  hipLaunchKernelGGL(psaT_kernel, dim3(N_ / 32, D1_ / 32, B_), dim3(256), 0, stream,
                     points_sa, xcat);
  hipLaunchKernelGGL(knn_interp_kernel, dim3(N_ / 128, B_), dim3(256), 0, stream,
                     xyz_sa, xyz_now, pnT, xcat);
  hipLaunchKernelGGL(gemm1_mfma_kernel, dim3(N_ / 128, 2, B_), dim3(256), 0, stream,
                     xcat, W0b, b0, y0b, stats);
  hipLaunchKernelGGL(bn_coef_kernel, dim3(1), dim3(256), 0, stream,
                     g0, be0, stats, coef, C1_);
  hipLaunchKernelGGL(bn0relu_kernel, dim3(2048), dim3(256), 0, stream,
                     y0b, coef, y0r);
  hipLaunchKernelGGL(gemm2_mfma_kernel, dim3(N_ / 128, 1, B_), dim3(256), 0, stream,
                     y0r, W1b, b1, y1b, stats + 512);
  hipLaunchKernelGGL(bn_coef_kernel, dim3(1), dim3(128), 0, stream,
                     g1, be1, stats + 512, coef + 512, C2_);
  hipLaunchKernelGGL(final_kernel, dim3(2048), dim3(256), 0, stream,
                     y1b, coef + 512, out);
}